// Round 25
// baseline (4964.642 us; speedup 1.0000x reference)
//
#include <hip/hip_runtime.h>
#include <hip/hip_bf16.h>
#include <math.h>

// ---------------------------------------------------------------------------
// FasterRCNN RPN — PASSING semantics. Round 23 staging (DMA + offset table),
// conv register tile widened to 4x8 per thread with 128-thread blocks
// (grid stays 1280 = 5 blocks/CU). FMA:LDS-read ratio 16:2 -> 32:3.
// Per-element arithmetic unchanged (bit-exact):
//   conv element: k=(c*9+tap) ascending, seq-fmaf in 384-chunks, chunk sums
//   added in order, + bias, relu        (OpenBLAS sgemm kc=384 model)
//   head element: same with chunks 384+128
//   downstream: strict f32, f32-score keys w/ low-index ties, f32 IOU vs 0.7f
//
// Workspace (bytes):
//   wtT    [18432][512]   f32  0 .. 37,748,736
//   h      [4][2500][512] f32  .. 58,228,736
//   scores [4][22500]     f32  .. 58,588,736
//   boxes  [4][22500][4]  f32  .. 60,028,736
//   keys   [4][32768]     u64  .. 61,077,312   (first 73,728 B double as the
//                                               offs[] table during conv)
//   masks  [4][2000][32]  u64  .. 63,125,312   (first 256 B double as zeropad
//                                               during conv)
// ---------------------------------------------------------------------------

#define CIN   2048
#define CH    512
#define NPOS  2500
#define NANCH 22500
#define NSORT 32768
#define BIMG  4
#define PRE_NMS_K 2000
#define TOP_N 1000
#define KWORDS 32
#define KTOT  18432
#define BK    32
#define NKT32 576      // KTOT/32

typedef const __attribute__((address_space(1))) void GPTR;
typedef __attribute__((address_space(3))) void LPTR;

__device__ __forceinline__ float read_dimf(const void* p) {
    int i32 = *(const int*)p;
    if (i32 >= 1 && i32 <= 1000000) return (float)i32;
    float f32 = *(const float*)p;
    if (f32 >= 1.f && f32 <= 1e6f) return f32;
    return (float)(*(const double*)p);
}

// --------- K0: wtT[(c*9+tap)*512+o] = w[(o*2048+c)*9+tap] --------------------
__global__ __launch_bounds__(256) void k_wtT(const float* __restrict__ w,
                                             float* __restrict__ wtT) {
    size_t idx = (size_t)blockIdx.x * 256 + threadIdx.x;   // 9,437,184 exact
    int o = idx & 511;
    size_t k = idx >> 9;            // c*9+tap
    int tap = (int)(k % 9);
    int c = (int)(k / 9);
    wtT[idx] = w[((size_t)o * CIN + c) * 9 + tap];
}

// --------- K0b: zero the 64-float zeropad block ------------------------------
__global__ void k_zero(float* z) { z[threadIdx.x] = 0.f; }

// --------- K0c: packed offset table: offs[k] = ((c*2500+dy*50+dx)+64)<<4|tap -
__global__ __launch_bounds__(256) void k_offs(int* __restrict__ offs) {
    int k = blockIdx.x * 256 + threadIdx.x;   // 18432 = 72 * 256 exact
    int c = k / 9, tap = k - c * 9;
    int dy = tap / 3 - 1, dx = tap % 3 - 1;
    int off = c * NPOS + dy * 50 + dx;
    offs[k] = ((off + 64) << 4) | tap;
}

// --------- K1: conv GEMM 64x64, 128 thr, 4x8/thread, DMA + offset table ------
__global__ __launch_bounds__(128) void k_conv_gemm(const float* __restrict__ feat0,
                                                   const float* __restrict__ wtT,
                                                   const float* __restrict__ bias,
                                                   float* __restrict__ h,
                                                   const float* __restrict__ zeropad,
                                                   const int* __restrict__ offs) {
#pragma clang fp contract(off)
    __shared__ __align__(16) float As[BK][64];   // 8 KB
    __shared__ __align__(16) float Bs[BK][64];   // 8 KB
    int tid = threadIdx.x;          // 0..127
    int lane = tid & 63;
    int wv = tid >> 6;              // wave id 0..1
    int tx = tid & 7;               // 8 N-groups * 8 = 64
    int ty = tid >> 3;              // 16 M-groups * 4 = 64
    int m0 = blockIdx.x * 64, n0 = blockIdx.y * 64;
    int b  = blockIdx.z;
    const float* feat = feat0 + (size_t)b * CIN * NPOS;

    int m  = m0 + lane;
    int y0 = m / 50, x0 = m - y0 * 50;
    bool mv = (m < NPOS);

    // per-lane tap-validity mask (9 bits), computed once
    unsigned tmask = 0;
    if (mv) {
#pragma unroll
        for (int tap = 0; tap < 9; ++tap) {
            int yy = y0 + tap / 3 - 1, xx = x0 + (tap % 3) - 1;
            if ((unsigned)yy < 50u && (unsigned)xx < 50u) tmask |= (1u << tap);
        }
    }
    const float* basep = feat + y0 * 50 + x0;        // per-lane base
    const float* bcol = wtT + n0 + ((lane & 15) << 2) + (size_t)(lane >> 4) * CH;

    float tot[4][8] = {};
    float chk[4][8] = {};

    for (int kt = 0; kt < NKT32; ++kt) {
        int k0 = kt * BK;
        __syncthreads();            // previous tile's reads complete
        // B: width-16 DMA, 4 issues/wave (each: 64 lanes x 16B = 4 rows)
#pragma unroll
        for (int e = 0; e < 4; ++e) {
            int r0 = wv * 16 + e * 4;
            const float* gsrc = bcol + (size_t)(k0 + r0) * CH;
            __builtin_amdgcn_global_load_lds((GPTR*)gsrc, (LPTR*)&Bs[r0][0], 16, 0, 0);
        }
        // A: width-4 DMA, 16 issues/wave; addr = basep + table offset.
        const int* op = offs + k0 + wv * 16;         // wave-uniform
#pragma unroll
        for (int e = 0; e < 16; ++e) {
            int r = wv * 16 + e;
            int pk = __builtin_amdgcn_readfirstlane(op[e]);
            int tap = pk & 15;
            int off = (pk >> 4) - 64;
            bool valid = (tmask >> tap) & 1u;
            const float* gsrc = valid ? (basep + off) : zeropad;
            __builtin_amdgcn_global_load_lds((GPTR*)gsrc, (LPTR*)&As[r][0], 4, 0, 0);
        }
        __syncthreads();            // drains vmcnt -> LDS populated
        // compute tile kt from LDS (bit-exact k-ascending chain)
#pragma unroll
        for (int kk = 0; kk < BK; ++kk) {
            float4 a4 = *(const float4*)&As[kk][ty * 4];
            float4 b0 = *(const float4*)&Bs[kk][tx * 8];
            float4 b1 = *(const float4*)&Bs[kk][tx * 8 + 4];
            float av[4] = {a4.x, a4.y, a4.z, a4.w};
            float bv[8] = {b0.x, b0.y, b0.z, b0.w, b1.x, b1.y, b1.z, b1.w};
#pragma unroll
            for (int ii = 0; ii < 4; ++ii)
#pragma unroll
                for (int jj = 0; jj < 8; ++jj)
                    chk[ii][jj] = fmaf(av[ii], bv[jj], chk[ii][jj]);
        }
        if ((kt % 12) == 11) {      // 384-element chunk boundary (12*32)
#pragma unroll
            for (int ii = 0; ii < 4; ++ii)
#pragma unroll
                for (int jj = 0; jj < 8; ++jj) {
                    tot[ii][jj] = tot[ii][jj] + chk[ii][jj];
                    chk[ii][jj] = 0.f;
                }
        }
    }

#pragma unroll
    for (int ii = 0; ii < 4; ++ii) {
        int mm = m0 + ty * 4 + ii;
        if (mm >= NPOS) continue;
#pragma unroll
        for (int jj = 0; jj < 8; ++jj) {
            int n = n0 + tx * 8 + jj;
            float v = tot[ii][jj] + bias[n];
            h[((size_t)b * NPOS + mm) * CH + n] = fmaxf(v, 0.f);
        }
    }
}

// -------- K2: f32 head, chunks 384+128 seq-FMA, strict f32 decode ------------
__global__ __launch_bounds__(256) void k_head32(const float* __restrict__ h,
                                                const float* __restrict__ wcls,
                                                const float* __restrict__ bcls,
                                                const float* __restrict__ wreg,
                                                const float* __restrict__ breg,
                                                const void* __restrict__ imh,
                                                const void* __restrict__ imw,
                                                float* __restrict__ scores,
                                                float* __restrict__ boxes) {
#pragma clang fp contract(off)
    __shared__ float sh[CH];
    __shared__ float sm[54];
    int p = blockIdx.x;
    int b = blockIdx.y;
    int t = threadIdx.x;

    for (int c = t; c < CH; c += 256)
        sh[c] = h[((size_t)b * NPOS + p) * CH + c];
    __syncthreads();

    if (t < 54) {
        const float* wr = (t < 18) ? (wcls + (size_t)t * CH)
                                   : (wreg + (size_t)(t - 18) * CH);
        float ch = 0.f;
        for (int c = 0; c < 384; ++c) ch = fmaf(sh[c], wr[c], ch);
        float tot = ch;
        ch = 0.f;
        for (int c = 384; c < 512; ++c) ch = fmaf(sh[c], wr[c], ch);
        tot = tot + ch;
        sm[t] = tot + ((t < 18) ? bcls[t] : breg[t - 18]);
    }
    __syncthreads();

    if (t < 9) {
        int a = t;
        float c0 = sm[a];
        float c1 = sm[9 + a];
        float mx = fmaxf(c0, c1);
        float e0 = expf(c0 - mx);
        float e1 = expf(c1 - mx);
        float sc = e1 / (e0 + e1);

        float dxv = sm[18 + a * 4 + 0];
        float dyv = sm[18 + a * 4 + 1];
        float dwv = sm[18 + a * 4 + 2];
        float dhv = sm[18 + a * 4 + 3];

        int y = p / 50, x = p % 50;
        const float sizes[3] = {128.f, 256.f, 512.f};
        const float rats[3]  = {0.5f, 1.f, 2.f};
        float sr  = sqrtf(rats[a % 3]);
        float wsf = sizes[a / 3] / sr;
        float hsf = sizes[a / 3] * sr;
        float cx = ((float)x + 0.5f) * 32.f;
        float cy = ((float)y + 0.5f) * 32.f;
        float x1 = cx - wsf / 2.f, y1 = cy - hsf / 2.f;
        float x2 = cx + wsf / 2.f, y2 = cy + hsf / 2.f;

        float aw = x2 - x1, ah = y2 - y1;
        float acx = x1 + 0.5f * aw, acy = y1 + 0.5f * ah;
        float pcx = dxv * aw + acx, pcy = dyv * ah + acy;
        float pw = expf(fminf(dwv, 4.f)) * aw;
        float ph = expf(fminf(dhv, 4.f)) * ah;
        float bx1 = pcx - pw / 2.f, by1 = pcy - ph / 2.f;
        float bx2 = pcx + pw / 2.f, by2 = pcy + ph / 2.f;
        float fw = read_dimf(imw), fh = read_dimf(imh);

        size_t n = (size_t)b * NANCH + (size_t)p * 9 + a;
        scores[n] = sc;
        float4 bx;
        bx.x = fminf(fmaxf(bx1, 0.f), fw);
        bx.y = fminf(fmaxf(by1, 0.f), fh);
        bx.z = fminf(fmaxf(bx2, 0.f), fw);
        bx.w = fminf(fmaxf(by2, 0.f), fh);
        ((float4*)boxes)[n] = bx;
    }
}

// ------------------------- K3: build sort keys -------------------------------
__global__ __launch_bounds__(256) void k_keys(const float* __restrict__ scores,
                                              unsigned long long* __restrict__ keys) {
    int t = blockIdx.x * 256 + threadIdx.x;
    int b = t >> 15, n = t & 32767;
    unsigned long long key = 0ULL;
    if (n < NANCH) {
        unsigned u = __float_as_uint(scores[(size_t)b * NANCH + n]);
        key = ((unsigned long long)u << 32) | (unsigned)(0xFFFFFFFFu - n);
    }
    keys[t] = key;
}

// -------------------- K4: bitonic sort (multi-kernel, descending) ------------
__device__ __forceinline__ void ce_swap(unsigned long long* s, int i, int l, bool down) {
    unsigned long long a = s[i], b = s[l];
    bool sw = down ? (a < b) : (a > b);
    if (sw) { s[i] = b; s[l] = a; }
}

__global__ __launch_bounds__(1024) void k_sort_local_full(unsigned long long* keys) {
    __shared__ unsigned long long s[2048];
    int t = threadIdx.x;
    size_t base = (size_t)blockIdx.x * 2048;
    int gbase = (blockIdx.x & 15) << 11;
    s[t] = keys[base + t]; s[t + 1024] = keys[base + t + 1024];
    __syncthreads();
    for (int k = 2; k <= 2048; k <<= 1) {
        for (int j = k >> 1; j >= 1; j >>= 1) {
            int i = ((t & ~(j - 1)) << 1) | (t & (j - 1));
            bool down = (((gbase + i) & k) == 0);
            ce_swap(s, i, i + j, down);
            __syncthreads();
        }
    }
    keys[base + t] = s[t]; keys[base + t + 1024] = s[t + 1024];
}

__global__ __launch_bounds__(1024) void k_sort_local_j(unsigned long long* keys, int k) {
    __shared__ unsigned long long s[2048];
    int t = threadIdx.x;
    size_t base = (size_t)blockIdx.x * 2048;
    int gbase = (blockIdx.x & 15) << 11;
    s[t] = keys[base + t]; s[t + 1024] = keys[base + t + 1024];
    __syncthreads();
    for (int j = 1024; j >= 1; j >>= 1) {
        int i = ((t & ~(j - 1)) << 1) | (t & (j - 1));
        bool down = (((gbase + i) & k) == 0);
        ce_swap(s, i, i + j, down);
        __syncthreads();
    }
    keys[base + t] = s[t]; keys[base + t + 1024] = s[t + 1024];
}

__global__ __launch_bounds__(256) void k_sort_gstep(unsigned long long* keys, int k, int j) {
    int t = blockIdx.x * 256 + threadIdx.x;
    int b = t >> 14, u = t & 16383;
    int i = ((u & ~(j - 1)) << 1) | (u & (j - 1));
    unsigned long long* g = keys + ((size_t)b << 15);
    bool down = ((i & k) == 0);
    unsigned long long a = g[i], bb = g[i + j];
    bool sw = down ? (a < bb) : (a > bb);
    if (sw) { g[i] = bb; g[i + j] = a; }
}

// ---------------- K5: IOU bitmasks, strict f32 (reference expr) --------------
__global__ __launch_bounds__(256) void k_masks(const unsigned long long* __restrict__ keys,
                                               const float* __restrict__ boxes,
                                               unsigned long long* __restrict__ masks) {
#pragma clang fp contract(off)
    int w = blockIdx.x & 31, b = blockIdx.x >> 5;
    __shared__ float4 jb[64];
    int t = threadIdx.x;
    const unsigned long long* kb_ = keys + ((size_t)b << 15);
    const float4* bxs = (const float4*)boxes + (size_t)b * NANCH;

    if (t < 64) {
        int j = w * 64 + t;
        float4 v = make_float4(0.f, 0.f, 0.f, 0.f);
        if (j < PRE_NMS_K) {
            unsigned n = 0xFFFFFFFFu - (unsigned)(kb_[j] & 0xFFFFFFFFu);
            v = bxs[n];
        }
        jb[t] = v;
    }
    __syncthreads();

    for (int i = t; i < PRE_NMS_K; i += 256) {
        unsigned ni = 0xFFFFFFFFu - (unsigned)(kb_[i] & 0xFFFFFFFFu);
        float4 bi = bxs[ni];
        float areai = (bi.z - bi.x) * (bi.w - bi.y);
        unsigned long long m = 0ULL;
        for (int bit = 0; bit < 64; ++bit) {
            int j = w * 64 + bit;
            if (j >= PRE_NMS_K || j == i) continue;
            float4 bj = jb[bit];
            float areaj = (bj.z - bj.x) * (bj.w - bj.y);
            float lx = fmaxf(bi.x, bj.x), ly = fmaxf(bi.y, bj.y);
            float rx = fminf(bi.z, bj.z), ry = fminf(bi.w, bj.w);
            float iw = fmaxf(rx - lx, 0.f), ih = fmaxf(ry - ly, 0.f);
            float inter = iw * ih;
            float den = areai + areaj;
            den = den - inter;
            den = den + 1e-9f;
            float iou = inter / den;
            if (iou > 0.7f) m |= (1ULL << bit);
        }
        masks[((size_t)b * PRE_NMS_K + i) * KWORDS + w] = m;
    }
}

// ---------------- K6: greedy NMS (bitmask) + select + f32 output -------------
__global__ __launch_bounds__(64) void k_nms(const unsigned long long* __restrict__ keys,
                                            const float* __restrict__ boxes,
                                            const unsigned long long* __restrict__ masks,
                                            float* __restrict__ out) {
    int b = blockIdx.x;
    int lane = threadIdx.x;
    const unsigned long long* mrow = masks + (size_t)b * PRE_NMS_K * KWORDS;
    const unsigned long long* kb_ = keys + ((size_t)b << 15);
    const float4* bxs = (const float4*)boxes + (size_t)b * NANCH;

    unsigned long long keep = 0ULL;   // lane l (<32) holds keep word l
    unsigned long long nextw = (lane < KWORDS) ? mrow[lane] : 0ULL;
    for (int i = 0; i < PRE_NMS_K; ++i) {
        unsigned long long mw = nextw;
        if (i + 1 < PRE_NMS_K)
            nextw = (lane < KWORDS) ? mrow[(size_t)(i + 1) * KWORDS + lane] : 0ULL;
        bool sup = __any((mw & keep) != 0ULL);
        if (!sup && lane == (i >> 6)) keep |= 1ULL << (i & 63);
    }

    __shared__ unsigned long long keepw[KWORDS];
    __shared__ int slist[TOP_N];
    if (lane < KWORDS) keepw[lane] = keep;
    __syncthreads();

    if (lane == 0) {
        int c = 0;
        for (int i = 0; i < PRE_NMS_K && c < TOP_N; ++i)
            if ((keepw[i >> 6] >> (i & 63)) & 1ULL) slist[c++] = i;
        for (int i = 0; i < PRE_NMS_K && c < TOP_N; ++i)
            if (!((keepw[i >> 6] >> (i & 63)) & 1ULL)) slist[c++] = i;
    }
    __syncthreads();

    for (int r = lane; r < TOP_N; r += 64) {
        int i = slist[r];
        unsigned n = 0xFFFFFFFFu - (unsigned)(kb_[i] & 0xFFFFFFFFu);
        ((float4*)out)[(size_t)b * TOP_N + r] = bxs[n];
    }
}

// ---------------------------------------------------------------------------
extern "C" void kernel_launch(void* const* d_in, const int* in_sizes, int n_in,
                              void* d_out, int out_size, void* d_ws, size_t ws_size,
                              hipStream_t stream) {
    const float* feat   = (const float*)d_in[0];
    const float* w_conv = (const float*)d_in[1];
    const float* b_conv = (const float*)d_in[2];
    const float* w_cls  = (const float*)d_in[3];
    const float* b_cls  = (const float*)d_in[4];
    const float* w_reg  = (const float*)d_in[5];
    const float* b_reg  = (const float*)d_in[6];
    const void*  img_h  = d_in[7];
    const void*  img_w  = d_in[8];

    char* ws = (char*)d_ws;
    float* wtT                 = (float*)(ws + 0);
    float* h                   = (float*)(ws + 37748736);
    float* scores              = (float*)(ws + 58228736);
    float* boxes               = (float*)(ws + 58588736);
    unsigned long long* keys   = (unsigned long long*)(ws + 60028736);
    unsigned long long* masks  = (unsigned long long*)(ws + 61077312);
    int*   offs                = (int*)(ws + 60028736);     // dead until k_keys
    float* zeropad             = (float*)(ws + 61077312);   // dead until k_masks

    k_wtT<<<(KTOT * CH) / 256, 256, 0, stream>>>(w_conv, wtT);
    k_zero<<<1, 64, 0, stream>>>(zeropad);
    k_offs<<<KTOT / 256, 256, 0, stream>>>(offs);

    // Conv: 40 x 8 x 4 = 1280 blocks, 128 threads, 64x64 tile, 4x8/thread
    k_conv_gemm<<<dim3(40, CH / 64, BIMG), 128, 0, stream>>>(
        feat, wtT, b_conv, h, zeropad, offs);

    // Head: 2500 x 4 blocks
    k_head32<<<dim3(NPOS, BIMG), 256, 0, stream>>>(
        h, w_cls, b_cls, w_reg, b_reg, img_h, img_w, scores, boxes);

    k_keys<<<(BIMG * NSORT) / 256, 256, 0, stream>>>(scores, keys);

    k_sort_local_full<<<BIMG * (NSORT / 2048), 1024, 0, stream>>>(keys);
    for (int k = 4096; k <= NSORT; k <<= 1) {
        for (int j = k >> 1; j >= 2048; j >>= 1)
            k_sort_gstep<<<(BIMG * NSORT / 2) / 256, 256, 0, stream>>>(keys, k, j);
        k_sort_local_j<<<BIMG * (NSORT / 2048), 1024, 0, stream>>>(keys, k);
    }

    k_masks<<<BIMG * KWORDS, 256, 0, stream>>>(keys, boxes, masks);
    k_nms<<<BIMG, 64, 0, stream>>>(keys, boxes, masks, (float*)d_out);
}

// Round 26
// 4066.916 us; speedup vs baseline: 1.2207x; 1.2207x over previous
//
#include <hip/hip_runtime.h>
#include <hip/hip_bf16.h>
#include <math.h>

// ---------------------------------------------------------------------------
// FasterRCNN RPN — PASSING semantics. Round 23 configuration (empirical
// optimum after r19/r20/r22/r24/r25 exploration): 64x64 tile, 256 threads,
// 4x4/thread, BK=32, single-buffer global_load_lds DMA staging + precomputed
// offset table + per-lane tap-validity mask.
// Per-element arithmetic (bit-exact vs np gold):
//   conv element: k=(c*9+tap) ascending, seq-fmaf in 384-chunks, chunk sums
//   added in order, + bias, relu        (OpenBLAS sgemm kc=384 model)
//   head element: same with chunks 384+128
//   downstream: strict f32, f32-score keys w/ low-index ties, f32 IOU vs 0.7f
//
// Workspace (bytes):
//   wtT    [18432][512]   f32  0 .. 37,748,736
//   h      [4][2500][512] f32  .. 58,228,736
//   scores [4][22500]     f32  .. 58,588,736
//   boxes  [4][22500][4]  f32  .. 60,028,736
//   keys   [4][32768]     u64  .. 61,077,312   (first 73,728 B double as the
//                                               offs[] table during conv)
//   masks  [4][2000][32]  u64  .. 63,125,312   (first 256 B double as zeropad
//                                               during conv)
// ---------------------------------------------------------------------------

#define CIN   2048
#define CH    512
#define NPOS  2500
#define NANCH 22500
#define NSORT 32768
#define BIMG  4
#define PRE_NMS_K 2000
#define TOP_N 1000
#define KWORDS 32
#define KTOT  18432
#define BK    32
#define NKT32 576      // KTOT/32

typedef const __attribute__((address_space(1))) void GPTR;
typedef __attribute__((address_space(3))) void LPTR;

__device__ __forceinline__ float read_dimf(const void* p) {
    int i32 = *(const int*)p;
    if (i32 >= 1 && i32 <= 1000000) return (float)i32;
    float f32 = *(const float*)p;
    if (f32 >= 1.f && f32 <= 1e6f) return f32;
    return (float)(*(const double*)p);
}

// --------- K0: wtT[(c*9+tap)*512+o] = w[(o*2048+c)*9+tap] --------------------
__global__ __launch_bounds__(256) void k_wtT(const float* __restrict__ w,
                                             float* __restrict__ wtT) {
    size_t idx = (size_t)blockIdx.x * 256 + threadIdx.x;   // 9,437,184 exact
    int o = idx & 511;
    size_t k = idx >> 9;            // c*9+tap
    int tap = (int)(k % 9);
    int c = (int)(k / 9);
    wtT[idx] = w[((size_t)o * CIN + c) * 9 + tap];
}

// --------- K0b: zero the 64-float zeropad block ------------------------------
__global__ void k_zero(float* z) { z[threadIdx.x] = 0.f; }

// --------- K0c: packed offset table: offs[k] = ((c*2500+dy*50+dx)+64)<<4|tap -
__global__ __launch_bounds__(256) void k_offs(int* __restrict__ offs) {
    int k = blockIdx.x * 256 + threadIdx.x;   // 18432 = 72 * 256 exact
    int c = k / 9, tap = k - c * 9;
    int dy = tap / 3 - 1, dx = tap % 3 - 1;
    int off = c * NPOS + dy * 50 + dx;
    offs[k] = ((off + 64) << 4) | tap;
}

// --------- K1: conv GEMM 64x64, 4x4/thread, DMA staging + offset table -------
__global__ __launch_bounds__(256) void k_conv_gemm(const float* __restrict__ feat0,
                                                   const float* __restrict__ wtT,
                                                   const float* __restrict__ bias,
                                                   float* __restrict__ h,
                                                   const float* __restrict__ zeropad,
                                                   const int* __restrict__ offs) {
#pragma clang fp contract(off)
    __shared__ __align__(16) float As[BK][64];
    __shared__ __align__(16) float Bs[BK][64];
    int tid = threadIdx.x;
    int lane = tid & 63;
    int wv = tid >> 6;              // wave id 0..3
    int tx = tid & 15, ty = tid >> 4;
    int m0 = blockIdx.x * 64, n0 = blockIdx.y * 64;
    int b  = blockIdx.z;
    const float* feat = feat0 + (size_t)b * CIN * NPOS;

    int m  = m0 + lane;
    int y0 = m / 50, x0 = m - y0 * 50;
    bool mv = (m < NPOS);

    // per-lane tap-validity mask (9 bits), computed once
    unsigned tmask = 0;
    if (mv) {
#pragma unroll
        for (int tap = 0; tap < 9; ++tap) {
            int yy = y0 + tap / 3 - 1, xx = x0 + (tap % 3) - 1;
            if ((unsigned)yy < 50u && (unsigned)xx < 50u) tmask |= (1u << tap);
        }
    }
    const float* basep = feat + y0 * 50 + x0;        // per-lane base
    // per-lane B address base (column part), computed once
    const float* bcol = wtT + n0 + ((lane & 15) << 2) + (size_t)(lane >> 4) * CH;

    float tot[4][4] = {};
    float chk[4][4] = {};

    for (int kt = 0; kt < NKT32; ++kt) {
        int k0 = kt * BK;
        __syncthreads();            // previous tile's reads complete
        // B: width-16 DMA, 2 issues/wave (each: 64 lanes x 16B = 4 rows)
#pragma unroll
        for (int e = 0; e < 2; ++e) {
            int r0 = wv * 8 + e * 4;
            const float* gsrc = bcol + (size_t)(k0 + r0) * CH;
            __builtin_amdgcn_global_load_lds((GPTR*)gsrc, (LPTR*)&Bs[r0][0], 16, 0, 0);
        }
        // A: width-4 DMA; per-issue addr = basep + table offset; validity from
        // the precomputed tap mask. OOB lanes read the zeropad.
        const int* op = offs + k0 + wv * 8;          // wave-uniform
#pragma unroll
        for (int e = 0; e < 8; ++e) {
            int r = wv * 8 + e;
            int pk = __builtin_amdgcn_readfirstlane(op[e]);
            int tap = pk & 15;
            int off = (pk >> 4) - 64;
            bool valid = (tmask >> tap) & 1u;
            const float* gsrc = valid ? (basep + off) : zeropad;
            __builtin_amdgcn_global_load_lds((GPTR*)gsrc, (LPTR*)&As[r][0], 4, 0, 0);
        }
        __syncthreads();            // drains vmcnt -> LDS populated
        // compute tile kt from LDS (bit-exact chain)
#pragma unroll
        for (int kk = 0; kk < BK; ++kk) {
            float4 a4 = *(const float4*)&As[kk][ty * 4];
            float4 b4 = *(const float4*)&Bs[kk][tx * 4];
            float av[4] = {a4.x, a4.y, a4.z, a4.w};
            float bv[4] = {b4.x, b4.y, b4.z, b4.w};
#pragma unroll
            for (int ii = 0; ii < 4; ++ii)
#pragma unroll
                for (int jj = 0; jj < 4; ++jj)
                    chk[ii][jj] = fmaf(av[ii], bv[jj], chk[ii][jj]);
        }
        if ((kt % 12) == 11) {      // 384-element chunk boundary (12*32)
#pragma unroll
            for (int ii = 0; ii < 4; ++ii)
#pragma unroll
                for (int jj = 0; jj < 4; ++jj) {
                    tot[ii][jj] = tot[ii][jj] + chk[ii][jj];
                    chk[ii][jj] = 0.f;
                }
        }
    }

#pragma unroll
    for (int ii = 0; ii < 4; ++ii) {
        int mm = m0 + ty * 4 + ii;
        if (mm >= NPOS) continue;
#pragma unroll
        for (int jj = 0; jj < 4; ++jj) {
            int n = n0 + tx * 4 + jj;
            float v = tot[ii][jj] + bias[n];
            h[((size_t)b * NPOS + mm) * CH + n] = fmaxf(v, 0.f);
        }
    }
}

// -------- K2: f32 head, chunks 384+128 seq-FMA, strict f32 decode ------------
__global__ __launch_bounds__(256) void k_head32(const float* __restrict__ h,
                                                const float* __restrict__ wcls,
                                                const float* __restrict__ bcls,
                                                const float* __restrict__ wreg,
                                                const float* __restrict__ breg,
                                                const void* __restrict__ imh,
                                                const void* __restrict__ imw,
                                                float* __restrict__ scores,
                                                float* __restrict__ boxes) {
#pragma clang fp contract(off)
    __shared__ float sh[CH];
    __shared__ float sm[54];
    int p = blockIdx.x;
    int b = blockIdx.y;
    int t = threadIdx.x;

    for (int c = t; c < CH; c += 256)
        sh[c] = h[((size_t)b * NPOS + p) * CH + c];
    __syncthreads();

    if (t < 54) {
        const float* wr = (t < 18) ? (wcls + (size_t)t * CH)
                                   : (wreg + (size_t)(t - 18) * CH);
        float ch = 0.f;
        for (int c = 0; c < 384; ++c) ch = fmaf(sh[c], wr[c], ch);
        float tot = ch;
        ch = 0.f;
        for (int c = 384; c < 512; ++c) ch = fmaf(sh[c], wr[c], ch);
        tot = tot + ch;
        sm[t] = tot + ((t < 18) ? bcls[t] : breg[t - 18]);
    }
    __syncthreads();

    if (t < 9) {
        int a = t;
        float c0 = sm[a];
        float c1 = sm[9 + a];
        float mx = fmaxf(c0, c1);
        float e0 = expf(c0 - mx);
        float e1 = expf(c1 - mx);
        float sc = e1 / (e0 + e1);

        float dxv = sm[18 + a * 4 + 0];
        float dyv = sm[18 + a * 4 + 1];
        float dwv = sm[18 + a * 4 + 2];
        float dhv = sm[18 + a * 4 + 3];

        int y = p / 50, x = p % 50;
        const float sizes[3] = {128.f, 256.f, 512.f};
        const float rats[3]  = {0.5f, 1.f, 2.f};
        float sr  = sqrtf(rats[a % 3]);
        float wsf = sizes[a / 3] / sr;
        float hsf = sizes[a / 3] * sr;
        float cx = ((float)x + 0.5f) * 32.f;
        float cy = ((float)y + 0.5f) * 32.f;
        float x1 = cx - wsf / 2.f, y1 = cy - hsf / 2.f;
        float x2 = cx + wsf / 2.f, y2 = cy + hsf / 2.f;

        float aw = x2 - x1, ah = y2 - y1;
        float acx = x1 + 0.5f * aw, acy = y1 + 0.5f * ah;
        float pcx = dxv * aw + acx, pcy = dyv * ah + acy;
        float pw = expf(fminf(dwv, 4.f)) * aw;
        float ph = expf(fminf(dhv, 4.f)) * ah;
        float bx1 = pcx - pw / 2.f, by1 = pcy - ph / 2.f;
        float bx2 = pcx + pw / 2.f, by2 = pcy + ph / 2.f;
        float fw = read_dimf(imw), fh = read_dimf(imh);

        size_t n = (size_t)b * NANCH + (size_t)p * 9 + a;
        scores[n] = sc;
        float4 bx;
        bx.x = fminf(fmaxf(bx1, 0.f), fw);
        bx.y = fminf(fmaxf(by1, 0.f), fh);
        bx.z = fminf(fmaxf(bx2, 0.f), fw);
        bx.w = fminf(fmaxf(by2, 0.f), fh);
        ((float4*)boxes)[n] = bx;
    }
}

// ------------------------- K3: build sort keys -------------------------------
__global__ __launch_bounds__(256) void k_keys(const float* __restrict__ scores,
                                              unsigned long long* __restrict__ keys) {
    int t = blockIdx.x * 256 + threadIdx.x;
    int b = t >> 15, n = t & 32767;
    unsigned long long key = 0ULL;
    if (n < NANCH) {
        unsigned u = __float_as_uint(scores[(size_t)b * NANCH + n]);
        key = ((unsigned long long)u << 32) | (unsigned)(0xFFFFFFFFu - n);
    }
    keys[t] = key;
}

// -------------------- K4: bitonic sort (multi-kernel, descending) ------------
__device__ __forceinline__ void ce_swap(unsigned long long* s, int i, int l, bool down) {
    unsigned long long a = s[i], b = s[l];
    bool sw = down ? (a < b) : (a > b);
    if (sw) { s[i] = b; s[l] = a; }
}

__global__ __launch_bounds__(1024) void k_sort_local_full(unsigned long long* keys) {
    __shared__ unsigned long long s[2048];
    int t = threadIdx.x;
    size_t base = (size_t)blockIdx.x * 2048;
    int gbase = (blockIdx.x & 15) << 11;
    s[t] = keys[base + t]; s[t + 1024] = keys[base + t + 1024];
    __syncthreads();
    for (int k = 2; k <= 2048; k <<= 1) {
        for (int j = k >> 1; j >= 1; j >>= 1) {
            int i = ((t & ~(j - 1)) << 1) | (t & (j - 1));
            bool down = (((gbase + i) & k) == 0);
            ce_swap(s, i, i + j, down);
            __syncthreads();
        }
    }
    keys[base + t] = s[t]; keys[base + t + 1024] = s[t + 1024];
}

__global__ __launch_bounds__(1024) void k_sort_local_j(unsigned long long* keys, int k) {
    __shared__ unsigned long long s[2048];
    int t = threadIdx.x;
    size_t base = (size_t)blockIdx.x * 2048;
    int gbase = (blockIdx.x & 15) << 11;
    s[t] = keys[base + t]; s[t + 1024] = keys[base + t + 1024];
    __syncthreads();
    for (int j = 1024; j >= 1; j >>= 1) {
        int i = ((t & ~(j - 1)) << 1) | (t & (j - 1));
        bool down = (((gbase + i) & k) == 0);
        ce_swap(s, i, i + j, down);
        __syncthreads();
    }
    keys[base + t] = s[t]; keys[base + t + 1024] = s[t + 1024];
}

__global__ __launch_bounds__(256) void k_sort_gstep(unsigned long long* keys, int k, int j) {
    int t = blockIdx.x * 256 + threadIdx.x;
    int b = t >> 14, u = t & 16383;
    int i = ((u & ~(j - 1)) << 1) | (u & (j - 1));
    unsigned long long* g = keys + ((size_t)b << 15);
    bool down = ((i & k) == 0);
    unsigned long long a = g[i], bb = g[i + j];
    bool sw = down ? (a < bb) : (a > bb);
    if (sw) { g[i] = bb; g[i + j] = a; }
}

// ---------------- K5: IOU bitmasks, strict f32 (reference expr) --------------
__global__ __launch_bounds__(256) void k_masks(const unsigned long long* __restrict__ keys,
                                               const float* __restrict__ boxes,
                                               unsigned long long* __restrict__ masks) {
#pragma clang fp contract(off)
    int w = blockIdx.x & 31, b = blockIdx.x >> 5;
    __shared__ float4 jb[64];
    int t = threadIdx.x;
    const unsigned long long* kb_ = keys + ((size_t)b << 15);
    const float4* bxs = (const float4*)boxes + (size_t)b * NANCH;

    if (t < 64) {
        int j = w * 64 + t;
        float4 v = make_float4(0.f, 0.f, 0.f, 0.f);
        if (j < PRE_NMS_K) {
            unsigned n = 0xFFFFFFFFu - (unsigned)(kb_[j] & 0xFFFFFFFFu);
            v = bxs[n];
        }
        jb[t] = v;
    }
    __syncthreads();

    for (int i = t; i < PRE_NMS_K; i += 256) {
        unsigned ni = 0xFFFFFFFFu - (unsigned)(kb_[i] & 0xFFFFFFFFu);
        float4 bi = bxs[ni];
        float areai = (bi.z - bi.x) * (bi.w - bi.y);
        unsigned long long m = 0ULL;
        for (int bit = 0; bit < 64; ++bit) {
            int j = w * 64 + bit;
            if (j >= PRE_NMS_K || j == i) continue;
            float4 bj = jb[bit];
            float areaj = (bj.z - bj.x) * (bj.w - bj.y);
            float lx = fmaxf(bi.x, bj.x), ly = fmaxf(bi.y, bj.y);
            float rx = fminf(bi.z, bj.z), ry = fminf(bi.w, bj.w);
            float iw = fmaxf(rx - lx, 0.f), ih = fmaxf(ry - ly, 0.f);
            float inter = iw * ih;
            float den = areai + areaj;
            den = den - inter;
            den = den + 1e-9f;
            float iou = inter / den;
            if (iou > 0.7f) m |= (1ULL << bit);
        }
        masks[((size_t)b * PRE_NMS_K + i) * KWORDS + w] = m;
    }
}

// ---------------- K6: greedy NMS (bitmask) + select + f32 output -------------
__global__ __launch_bounds__(64) void k_nms(const unsigned long long* __restrict__ keys,
                                            const float* __restrict__ boxes,
                                            const unsigned long long* __restrict__ masks,
                                            float* __restrict__ out) {
    int b = blockIdx.x;
    int lane = threadIdx.x;
    const unsigned long long* mrow = masks + (size_t)b * PRE_NMS_K * KWORDS;
    const unsigned long long* kb_ = keys + ((size_t)b << 15);
    const float4* bxs = (const float4*)boxes + (size_t)b * NANCH;

    unsigned long long keep = 0ULL;   // lane l (<32) holds keep word l
    unsigned long long nextw = (lane < KWORDS) ? mrow[lane] : 0ULL;
    for (int i = 0; i < PRE_NMS_K; ++i) {
        unsigned long long mw = nextw;
        if (i + 1 < PRE_NMS_K)
            nextw = (lane < KWORDS) ? mrow[(size_t)(i + 1) * KWORDS + lane] : 0ULL;
        bool sup = __any((mw & keep) != 0ULL);
        if (!sup && lane == (i >> 6)) keep |= 1ULL << (i & 63);
    }

    __shared__ unsigned long long keepw[KWORDS];
    __shared__ int slist[TOP_N];
    if (lane < KWORDS) keepw[lane] = keep;
    __syncthreads();

    if (lane == 0) {
        int c = 0;
        for (int i = 0; i < PRE_NMS_K && c < TOP_N; ++i)
            if ((keepw[i >> 6] >> (i & 63)) & 1ULL) slist[c++] = i;
        for (int i = 0; i < PRE_NMS_K && c < TOP_N; ++i)
            if (!((keepw[i >> 6] >> (i & 63)) & 1ULL)) slist[c++] = i;
    }
    __syncthreads();

    for (int r = lane; r < TOP_N; r += 64) {
        int i = slist[r];
        unsigned n = 0xFFFFFFFFu - (unsigned)(kb_[i] & 0xFFFFFFFFu);
        ((float4*)out)[(size_t)b * TOP_N + r] = bxs[n];
    }
}

// ---------------------------------------------------------------------------
extern "C" void kernel_launch(void* const* d_in, const int* in_sizes, int n_in,
                              void* d_out, int out_size, void* d_ws, size_t ws_size,
                              hipStream_t stream) {
    const float* feat   = (const float*)d_in[0];
    const float* w_conv = (const float*)d_in[1];
    const float* b_conv = (const float*)d_in[2];
    const float* w_cls  = (const float*)d_in[3];
    const float* b_cls  = (const float*)d_in[4];
    const float* w_reg  = (const float*)d_in[5];
    const float* b_reg  = (const float*)d_in[6];
    const void*  img_h  = d_in[7];
    const void*  img_w  = d_in[8];

    char* ws = (char*)d_ws;
    float* wtT                 = (float*)(ws + 0);
    float* h                   = (float*)(ws + 37748736);
    float* scores              = (float*)(ws + 58228736);
    float* boxes               = (float*)(ws + 58588736);
    unsigned long long* keys   = (unsigned long long*)(ws + 60028736);
    unsigned long long* masks  = (unsigned long long*)(ws + 61077312);
    int*   offs                = (int*)(ws + 60028736);     // dead until k_keys
    float* zeropad             = (float*)(ws + 61077312);   // dead until k_masks

    k_wtT<<<(KTOT * CH) / 256, 256, 0, stream>>>(w_conv, wtT);
    k_zero<<<1, 64, 0, stream>>>(zeropad);
    k_offs<<<KTOT / 256, 256, 0, stream>>>(offs);

    // Conv: 40 x 8 x 4 = 1280 blocks, 64x64 tile, DMA staging + offset table
    k_conv_gemm<<<dim3(40, CH / 64, BIMG), 256, 0, stream>>>(
        feat, wtT, b_conv, h, zeropad, offs);

    // Head: 2500 x 4 blocks
    k_head32<<<dim3(NPOS, BIMG), 256, 0, stream>>>(
        h, w_cls, b_cls, w_reg, b_reg, img_h, img_w, scores, boxes);

    k_keys<<<(BIMG * NSORT) / 256, 256, 0, stream>>>(scores, keys);

    k_sort_local_full<<<BIMG * (NSORT / 2048), 1024, 0, stream>>>(keys);
    for (int k = 4096; k <= NSORT; k <<= 1) {
        for (int j = k >> 1; j >= 2048; j >>= 1)
            k_sort_gstep<<<(BIMG * NSORT / 2) / 256, 256, 0, stream>>>(keys, k, j);
        k_sort_local_j<<<BIMG * (NSORT / 2048), 1024, 0, stream>>>(keys, k);
    }

    k_masks<<<BIMG * KWORDS, 256, 0, stream>>>(keys, boxes, masks);
    k_nms<<<BIMG, 64, 0, stream>>>(keys, boxes, masks, (float*)d_out);
}